// Round 8
// baseline (247.610 us; speedup 1.0000x reference)
//
#include <hip/hip_runtime.h>

constexpr int NN   = 50000;
constexpr int PADN = 50048;       // 391*128, padded rows
constexpr int KD   = 128;
constexpr int RR   = 8;
constexpr int NSEG = RR * NN;     // 400000
constexpr int NBLK = 196;         // scan blocks: 196*2048 = 401408 >= NSEG
constexpr int PADSEG = NBLK * 2048;

typedef __attribute__((ext_vector_type(8))) short short8;
typedef __attribute__((ext_vector_type(4))) float f32x4;

__device__ __forceinline__ float bflo(unsigned u){ return __uint_as_float(u << 16); }
__device__ __forceinline__ float bfhi(unsigned u){ return __uint_as_float(u & 0xffff0000u); }
__device__ __forceinline__ unsigned pk_bf16(float a, float b){
  unsigned ua = __float_as_uint(a), ub = __float_as_uint(b);
  ua = (ua + 0x7fffu + ((ua >> 16) & 1u)) >> 16;
  ub = (ub + 0x7fffu + ((ub >> 16) & 1u)) & 0xffff0000u;
  return (ua & 0xffffu) | ub;
}
__device__ __forceinline__ unsigned short bf1(float a){
  unsigned ua = __float_as_uint(a);
  return (unsigned short)((ua + 0x7fffu + ((ua >> 16) & 1u)) >> 16);
}

// ---------------- pass 1: convert x to bf16 + rank-assign (single atomic pass) ----
__global__ __launch_bounds__(256)
void convert_count_rank(const float* __restrict__ x, unsigned* __restrict__ xb,
                        const int* __restrict__ dst, const int* __restrict__ et,
                        int E, int* __restrict__ cnt, int* __restrict__ rank) {
  const int idx = blockIdx.x * 256 + threadIdx.x;
  if (idx < E) rank[idx] = atomicAdd(&cnt[et[idx] * NN + dst[idx]], 1);
  if (idx < PADN * 16) {
    const int row = idx >> 4, o = (idx & 15) * 8;
    uint4 v = make_uint4(0u, 0u, 0u, 0u);
    if (row < NN) {
      float4 a = *(const float4*)&x[(size_t)row * KD + o];
      float4 b = *(const float4*)&x[(size_t)row * KD + o + 4];
      v.x = pk_bf16(a.x, a.y); v.y = pk_bf16(a.z, a.w);
      v.z = pk_bf16(b.x, b.y); v.w = pk_bf16(b.z, b.w);
    }
    *(uint4*)&xb[(size_t)idx * 4] = v;
  }
}

// hierarchical exclusive scan (no global atomics)
__global__ __launch_bounds__(256)
void scan_block(const int* __restrict__ cnt, int* __restrict__ fillpos,
                int* __restrict__ blkSum) {
  const int t = threadIdx.x;
  const int base = blockIdx.x * 2048 + t * 8;
  const int4 a = *(const int4*)&cnt[base];
  const int4 b = *(const int4*)&cnt[base + 4];
  const int s8[8] = {a.x, a.y, a.z, a.w, b.x, b.y, b.z, b.w};
  int tsum = 0;
#pragma unroll
  for (int i = 0; i < 8; ++i) tsum += s8[i];
  int inc = tsum;
#pragma unroll
  for (int o = 1; o < 64; o <<= 1) {
    int v = __shfl_up(inc, o);
    if ((t & 63) >= o) inc += v;
  }
  __shared__ int wsum[4];
  if ((t & 63) == 63) wsum[t >> 6] = inc;
  __syncthreads();
  int wpre = 0;
#pragma unroll
  for (int w = 0; w < 4; ++w) if (w < (t >> 6)) wpre += wsum[w];
  int run = wpre + inc - tsum;
  int o8[8];
#pragma unroll
  for (int i = 0; i < 8; ++i) { o8[i] = run; run += s8[i]; }
  *(int4*)&fillpos[base]     = make_int4(o8[0], o8[1], o8[2], o8[3]);
  *(int4*)&fillpos[base + 4] = make_int4(o8[4], o8[5], o8[6], o8[7]);
  if (t == 255) blkSum[blockIdx.x] = wpre + inc;
}

__global__ __launch_bounds__(256)
void scan_tops(int* __restrict__ blkSum) {
  const int t = threadIdx.x;
  const int v = (t < NBLK) ? blkSum[t] : 0;
  int inc = v;
#pragma unroll
  for (int o = 1; o < 64; o <<= 1) {
    int u = __shfl_up(inc, o);
    if ((t & 63) >= o) inc += u;
  }
  __shared__ int wsum[4];
  if ((t & 63) == 63) wsum[t >> 6] = inc;
  __syncthreads();
  int wpre = 0;
#pragma unroll
  for (int w = 0; w < 4; ++w) if (w < (t >> 6)) wpre += wsum[w];
  if (t < NBLK) blkSum[t] = wpre + inc - v;
}

__global__ __launch_bounds__(256)
void scan_apply(int* __restrict__ fillpos, const int* __restrict__ blkSum) {
  const int base = blockIdx.x * 2048 + threadIdx.x * 8;
  const int off = blkSum[blockIdx.x];
  int4 a = *(int4*)&fillpos[base];
  int4 b = *(int4*)&fillpos[base + 4];
  a.x += off; a.y += off; a.z += off; a.w += off;
  b.x += off; b.y += off; b.z += off; b.w += off;
  *(int4*)&fillpos[base]     = a;
  *(int4*)&fillpos[base + 4] = b;
}

// ---------------- pass 2: scatter srcs to sorted order, NO atomics ----------------
__global__ __launch_bounds__(256)
void fill_scatter(const int* __restrict__ src, const int* __restrict__ dst,
                  const int* __restrict__ et, const int* __restrict__ rank,
                  int E, const int* __restrict__ segbase, int* __restrict__ srt) {
  const int e = blockIdx.x * 256 + threadIdx.x;
  if (e < E) {
    const int seg = et[e] * NN + dst[e];
    srt[segbase[seg] + rank[e]] = src[e];
  }
}

// Wt1[9][128][128] and Wt2[9][64][128] bf16, transposed, in one dispatch
__global__ __launch_bounds__(256)
void prep_w(const float* __restrict__ W1, const float* __restrict__ root1,
            const float* __restrict__ W2, const float* __restrict__ root2,
            unsigned short* __restrict__ Wt1, unsigned short* __restrict__ Wt2) {
  int idx = blockIdx.x * 256 + threadIdx.x;
  if (idx < 9 * 128 * KD) {
    const int k = idx & 127;
    const int n = (idx >> 7) & 127;
    const int ch = idx >> 14;
    const float v = (ch < 8) ? W1[((size_t)ch * KD + k) * 128 + n] : root1[(size_t)k * 128 + n];
    Wt1[idx] = bf1(v);
  } else {
    idx -= 9 * 128 * KD;
    const int k = idx & 127;
    const int n = (idx >> 7) & 63;
    const int ch = idx >> 13;
    const float v = (ch < 8) ? W2[((size_t)ch * KD + k) * 64 + n] : root2[(size_t)k * 64 + n];
    Wt2[idx] = bf1(v);
  }
}

// ---------------- wide transform GEMM: Y[M, NCOLS] = A[M,128] @ Wt^T ----------------
// BM=128, BK=64, 256 threads = 4 waves, LDS XOR-swizzled. grid=(M/128, NCOLS/BN).
template<int BN, int NCOLS>
__global__ __launch_bounds__(256)
void gemm_y(const unsigned short* __restrict__ A,    // [PADN][128] bf16
            const unsigned short* __restrict__ Wt,   // [NCOLS][128] bf16 (row=out col)
            unsigned short* __restrict__ Y) {        // [PADN][NCOLS] bf16
  constexpr int WM = (BN == 128) ? 64 : 32;
  constexpr int MF = WM / 16;
  constexpr int NF = 4;
  constexpr int WAVES_N = BN / 64;

  __shared__ uint4 ldsv[(128 * 128 + BN * 128) / 16];
  char* As = (char*)ldsv;                 // [128][128B] swizzled
  char* Bs = (char*)ldsv + 128 * 128;     // [BN][128B]  swizzled

  const int t = threadIdx.x;
  const int l = t & 63;
  const int w = t >> 6;
  const int wr = w / WAVES_N;
  const int wc = w % WAVES_N;
  const int row0 = blockIdx.x * 128;
  const int col0 = blockIdx.y * BN;
  const unsigned short* bP = Wt + (size_t)col0 * KD;
  const int l15 = l & 15, lq = l >> 4;

  f32x4 acc[MF][NF];
#pragma unroll
  for (int mi = 0; mi < MF; ++mi)
#pragma unroll
    for (int ni = 0; ni < NF; ++ni) acc[mi][ni] = (f32x4){0.f, 0.f, 0.f, 0.f};

#pragma unroll
  for (int kt = 0; kt < 2; ++kt) {
    __syncthreads();
#pragma unroll
    for (int i = 0; i < 4; ++i) {        // stage A: 128 rows x 64 bf16
      const int s = t + i * 256;
      const int r = s >> 3, c16 = s & 7;
      uint4 v = *(const uint4*)(A + (size_t)(row0 + r) * KD + kt * 64 + c16 * 8);
      *(uint4*)(As + r * 128 + ((c16 ^ (r & 7)) * 16)) = v;
    }
#pragma unroll
    for (int i = 0; i < BN / 32; ++i) {  // stage B: BN rows x 64 bf16
      const int s = t + i * 256;
      const int r = s >> 3, c16 = s & 7;
      uint4 v = *(const uint4*)(bP + (size_t)r * KD + kt * 64 + c16 * 8);
      *(uint4*)(Bs + r * 128 + ((c16 ^ (r & 7)) * 16)) = v;
    }
    __syncthreads();
#pragma unroll
    for (int ks = 0; ks < 2; ++ks) {
      short8 bfr[NF];
#pragma unroll
      for (int ni = 0; ni < NF; ++ni) {
        const int br = wc * 64 + ni * 16 + l15;
        bfr[ni] = *(const short8*)(Bs + br * 128 + (((ks * 4 + lq) ^ (br & 7)) * 16));
      }
#pragma unroll
      for (int mi = 0; mi < MF; ++mi) {
        const int ar = wr * WM + mi * 16 + l15;
        short8 af = *(const short8*)(As + ar * 128 + (((ks * 4 + lq) ^ (ar & 7)) * 16));
#pragma unroll
        for (int ni = 0; ni < NF; ++ni)
          acc[mi][ni] = __builtin_amdgcn_mfma_f32_16x16x32_bf16(af, bfr[ni], acc[mi][ni], 0, 0, 0);
      }
    }
  }
  // epilogue: plain bf16 store (pad rows get zeros since A pad rows are zero)
#pragma unroll
  for (int ni = 0; ni < NF; ++ni) {
    const int col = col0 + wc * 64 + ni * 16 + l15;
#pragma unroll
    for (int mi = 0; mi < MF; ++mi) {
#pragma unroll
      for (int q = 0; q < 4; ++q) {
        const int grow = row0 + wr * WM + mi * 16 + lq * 4 + q;
        Y[(size_t)grow * NCOLS + col] = bf1(acc[mi][ni][q]);
      }
    }
  }
}

// ---------------- gather-reduce: Out[d] = self + bias + sum_r mean_r(Y slices) ----
// 16 lanes per dst node. FO=128 (layer1, bf16 out + relu) / FO=64 (layer2, fp32 out).
template<int FO, bool RELU, bool OUTBF16>
__global__ __launch_bounds__(256)
void gather_out(const unsigned* __restrict__ Y,      // [PADN][9*FO/2] uints
                const int* __restrict__ srt,
                const int* __restrict__ segbase, const int* __restrict__ cnt,
                const float* __restrict__ bias,
                void* __restrict__ Out) {
  constexpr int RS  = FO / 2;        // uints per r-slice (64 / 32)
  constexpr int ROW = RS * 9;        // uints per Y row  (576 / 288)
  constexpr int UPL = FO / 32;       // uints per lane   (4 / 2)
  const int d = blockIdx.x * 16 + (threadIdx.x >> 4);
  const int lane = threadIdx.x & 15;
  const int l = threadIdx.x & 63;

  // lanes 0..7 fetch cnt for r=0..7, lanes 8..15 fetch segbase
  int meta = 0;
  if (d < NN) {
    const int idx = (lane & 7) * NN + d;
    meta = (lane < 8) ? cnt[idx] : segbase[idx];
  }

  float acc[2 * UPL] = {};
#pragma unroll
  for (int r = 0; r < 8; ++r) {
    const int c    = __shfl(meta, (l & 48) + r);
    const int base = __shfl(meta, (l & 48) + 8 + r);
    float tmp[2 * UPL] = {};
    int i = 0;
    for (; i + 1 < c; i += 2) {
      const int s0 = srt[base + i], s1 = srt[base + i + 1];
      if (FO == 128) {
        const uint4 v0 = *(const uint4*)&Y[(size_t)s0 * ROW + r * RS + lane * UPL];
        const uint4 v1 = *(const uint4*)&Y[(size_t)s1 * ROW + r * RS + lane * UPL];
        tmp[0] += bflo(v0.x) + bflo(v1.x); tmp[1] += bfhi(v0.x) + bfhi(v1.x);
        tmp[2] += bflo(v0.y) + bflo(v1.y); tmp[3] += bfhi(v0.y) + bfhi(v1.y);
        tmp[4] += bflo(v0.z) + bflo(v1.z); tmp[5] += bfhi(v0.z) + bfhi(v1.z);
        tmp[6] += bflo(v0.w) + bflo(v1.w); tmp[7] += bfhi(v0.w) + bfhi(v1.w);
      } else {
        const uint2 v0 = *(const uint2*)&Y[(size_t)s0 * ROW + r * RS + lane * UPL];
        const uint2 v1 = *(const uint2*)&Y[(size_t)s1 * ROW + r * RS + lane * UPL];
        tmp[0] += bflo(v0.x) + bflo(v1.x); tmp[1] += bfhi(v0.x) + bfhi(v1.x);
        tmp[2] += bflo(v0.y) + bflo(v1.y); tmp[3] += bfhi(v0.y) + bfhi(v1.y);
      }
    }
    if (i < c) {
      const int s0 = srt[base + i];
      if (FO == 128) {
        const uint4 v0 = *(const uint4*)&Y[(size_t)s0 * ROW + r * RS + lane * UPL];
        tmp[0] += bflo(v0.x); tmp[1] += bfhi(v0.x);
        tmp[2] += bflo(v0.y); tmp[3] += bfhi(v0.y);
        tmp[4] += bflo(v0.z); tmp[5] += bfhi(v0.z);
        tmp[6] += bflo(v0.w); tmp[7] += bfhi(v0.w);
      } else {
        const uint2 v0 = *(const uint2*)&Y[(size_t)s0 * ROW + r * RS + lane * UPL];
        tmp[0] += bflo(v0.x); tmp[1] += bfhi(v0.x);
        tmp[2] += bflo(v0.y); tmp[3] += bfhi(v0.y);
      }
    }
    const float inv = (c > 0) ? 1.0f / (float)c : 0.0f;
#pragma unroll
    for (int j = 0; j < 2 * UPL; ++j) acc[j] += tmp[j] * inv;
  }

  if (d >= NN) {   // pad rows: zero-fill bf16 intermediate so GEMM2 A-reads are clean
    if (OUTBF16) {
      uint4 z = make_uint4(0u, 0u, 0u, 0u);
      *(uint4*)&((unsigned*)Out)[(size_t)d * (FO / 2) + lane * UPL] = z;
    }
    return;
  }

  // self slice (ch 8) + bias, relu, store
  float v[2 * UPL];
  if (FO == 128) {
    const uint4 sv = *(const uint4*)&Y[(size_t)d * ROW + 8 * RS + lane * UPL];
    v[0] = bflo(sv.x); v[1] = bfhi(sv.x); v[2] = bflo(sv.y); v[3] = bfhi(sv.y);
    v[4] = bflo(sv.z); v[5] = bfhi(sv.z); v[6] = bflo(sv.w); v[7] = bfhi(sv.w);
    const float4 b0 = *(const float4*)&bias[lane * 8];
    const float4 b1 = *(const float4*)&bias[lane * 8 + 4];
    v[0] += b0.x; v[1] += b0.y; v[2] += b0.z; v[3] += b0.w;
    v[4] += b1.x; v[5] += b1.y; v[6] += b1.z; v[7] += b1.w;
  } else {
    const uint2 sv = *(const uint2*)&Y[(size_t)d * ROW + 8 * RS + lane * UPL];
    v[0] = bflo(sv.x); v[1] = bfhi(sv.x); v[2] = bflo(sv.y); v[3] = bfhi(sv.y);
    const float4 b0 = *(const float4*)&bias[lane * 4];
    v[0] += b0.x; v[1] += b0.y; v[2] += b0.z; v[3] += b0.w;
  }
#pragma unroll
  for (int j = 0; j < 2 * UPL; ++j) {
    v[j] += acc[j];
    if (RELU) v[j] = fmaxf(v[j], 0.f);
  }
  if (OUTBF16) {
    uint4 o;
    o.x = pk_bf16(v[0], v[1]); o.y = pk_bf16(v[2], v[3]);
    o.z = pk_bf16(v[4], v[5]); o.w = pk_bf16(v[6], v[7]);
    *(uint4*)&((unsigned*)Out)[(size_t)d * 64 + lane * 4] = o;
  } else {
    float4 o; o.x = v[0]; o.y = v[1]; o.z = v[2]; o.w = v[3];
    *(float4*)&((float*)Out)[(size_t)d * 64 + lane * 4] = o;
  }
}

// ---------------- launch ----------------
extern "C" void kernel_launch(void* const* d_in, const int* in_sizes, int n_in,
                              void* d_out, int out_size, void* d_ws, size_t ws_size,
                              hipStream_t stream) {
  const float* x     = (const float*)d_in[0];
  const int*   ei    = (const int*)d_in[1];
  const int*   et    = (const int*)d_in[2];
  const float* W1    = (const float*)d_in[3];
  const float* root1 = (const float*)d_in[4];
  const float* b1    = (const float*)d_in[5];
  const float* W2    = (const float*)d_in[6];
  const float* root2 = (const float*)d_in[7];
  const float* b2    = (const float*)d_in[8];
  float* out = (float*)d_out;

  const int E = in_sizes[2];
  const int* src  = ei;
  const int* dstv = ei + E;

  // workspace layout (~141 MB, 16B-aligned)
  char* ws = (char*)d_ws;
  unsigned short* xb  = (unsigned short*)ws;                 // 12,812,288 B
  unsigned short* hb  = (unsigned short*)(ws + 12812288);    // 12,812,288 B
  unsigned short* Y   = (unsigned short*)(ws + 25624576);    // 115,310,592 B (Y1; Y2 aliased)
  unsigned short* Wt1 = (unsigned short*)(ws + 140935168);   //    294,912 B
  unsigned short* Wt2 = (unsigned short*)(ws + 141230080);   //    147,456 B
  int* cnt     = (int*)(ws + 141377536);                     //  1,605,632 B
  int* fillpos = (int*)(ws + 142983168);                     //  1,605,632 B
  int* blkSum  = (int*)(ws + 144588800);                     //      1,024 B
  int* srt     = (int*)(ws + 144589824);                     //  3,200,000 B (ends 147,789,824)
  int* rank    = (int*)Y;   // aliased: consumed by fill_scatter before gemm_y writes Y

  // build segment structure: rank-assign (+x convert) -> scan -> scatter
  hipMemsetAsync(cnt, 0, sizeof(int) * (size_t)PADSEG, stream);
  convert_count_rank<<<PADN * 16 / 256, 256, 0, stream>>>(x, (unsigned*)xb, dstv, et, E, cnt, rank);
  scan_block<<<NBLK, 256, 0, stream>>>(cnt, fillpos, blkSum);
  scan_tops<<<1, 256, 0, stream>>>(blkSum);
  scan_apply<<<NBLK, 256, 0, stream>>>(fillpos, blkSum);
  fill_scatter<<<(E + 255) / 256, 256, 0, stream>>>(src, dstv, et, rank, E, fillpos, srt);

  prep_w<<<(9 * 128 * KD + 9 * 64 * KD) / 256, 256, 0, stream>>>(W1, root1, W2, root2, Wt1, Wt2);

  const int mBlocks = PADN / 128;       // 391

  // layer 1: Y1 = xb @ [W1_r..., root1]  (N=1152), then gather-reduce -> hb (bf16)
  gemm_y<128, 1152><<<dim3(mBlocks, 9), 256, 0, stream>>>(xb, Wt1, Y);
  gather_out<128, true, true><<<PADN / 16, 256, 0, stream>>>(
      (const unsigned*)Y, srt, fillpos, cnt, b1, hb);

  // layer 2: Y2 = hb @ [W2_r..., root2]  (N=576), then gather-reduce -> out (fp32)
  gemm_y<64, 576><<<dim3(mBlocks, 9), 256, 0, stream>>>(hb, Wt2, Y);
  gather_out<64, false, false><<<NN / 16, 256, 0, stream>>>(
      (const unsigned*)Y, srt, fillpos, cnt, b2, out);
}

// Round 9
// 214.676 us; speedup vs baseline: 1.1534x; 1.1534x over previous
//
#include <hip/hip_runtime.h>

constexpr int NN   = 50000;
constexpr int PADN = 50048;       // 391*128, padded rows
constexpr int KD   = 128;
constexpr int RR   = 8;
constexpr int NSEG = RR * NN;     // 400000
constexpr int NBLK = 196;         // scan blocks: 196*2048 = 401408 >= NSEG
constexpr int PADSEG = NBLK * 2048;
// segment order: segidx(r,d) = 2*((r>>1)*NN + d) + (r&1)
// packed counters: cntp[(r>>1)*NN + d], 16-bit field (r&1)

typedef __attribute__((ext_vector_type(8))) short short8;
typedef __attribute__((ext_vector_type(4))) float f32x4;
typedef __attribute__((ext_vector_type(4))) unsigned int u32x4;

__device__ __forceinline__ float bflo(unsigned u){ return __uint_as_float(u << 16); }
__device__ __forceinline__ float bfhi(unsigned u){ return __uint_as_float(u & 0xffff0000u); }
__device__ __forceinline__ unsigned pk_bf16(float a, float b){
  unsigned ua = __float_as_uint(a), ub = __float_as_uint(b);
  ua = (ua + 0x7fffu + ((ua >> 16) & 1u)) >> 16;
  ub = (ub + 0x7fffu + ((ub >> 16) & 1u)) & 0xffff0000u;
  return (ua & 0xffffu) | ub;
}
__device__ __forceinline__ unsigned short bf1(float a){
  unsigned ua = __float_as_uint(a);
  return (unsigned short)((ua + 0x7fffu + ((ua >> 16) & 1u)) >> 16);
}

// ---------------- pass 1: convert x to bf16 + packed rank-assign ----------------
__global__ __launch_bounds__(256)
void convert_count_rank(const float* __restrict__ x, unsigned* __restrict__ xb,
                        const int* __restrict__ dst, const int* __restrict__ et,
                        int E, unsigned* __restrict__ cntp, int* __restrict__ rank) {
  const int idx = blockIdx.x * 256 + threadIdx.x;
  if (idx < E) {
    const int r = et[idx], d = dst[idx];
    const int sh = (r & 1) * 16;
    const unsigned old = atomicAdd(&cntp[(r >> 1) * NN + d], 1u << sh);
    rank[idx] = (old >> sh) & 0xffffu;
  }
  if (idx < PADN * 16) {
    const int row = idx >> 4, o = (idx & 15) * 8;
    uint4 v = make_uint4(0u, 0u, 0u, 0u);
    if (row < NN) {
      float4 a = *(const float4*)&x[(size_t)row * KD + o];
      float4 b = *(const float4*)&x[(size_t)row * KD + o + 4];
      v.x = pk_bf16(a.x, a.y); v.y = pk_bf16(a.z, a.w);
      v.z = pk_bf16(b.x, b.y); v.w = pk_bf16(b.z, b.w);
    }
    *(uint4*)&xb[(size_t)idx * 4] = v;
  }
}

// hierarchical exclusive scan over segidx order; reads PACKED counters.
// thread t handles 8 segments = 4 packed words.
__global__ __launch_bounds__(256)
void scan_block(const unsigned* __restrict__ cntp, int* __restrict__ fillpos,
                int* __restrict__ blkSum) {
  const int t = threadIdx.x;
  const int wbase = blockIdx.x * 1024 + t * 4;     // packed-word index
  const uint4 wv = *(const uint4*)&cntp[wbase];
  int s8[8];
  s8[0] = wv.x & 0xffff; s8[1] = wv.x >> 16;
  s8[2] = wv.y & 0xffff; s8[3] = wv.y >> 16;
  s8[4] = wv.z & 0xffff; s8[5] = wv.z >> 16;
  s8[6] = wv.w & 0xffff; s8[7] = wv.w >> 16;
  int tsum = 0;
#pragma unroll
  for (int i = 0; i < 8; ++i) tsum += s8[i];
  int inc = tsum;
#pragma unroll
  for (int o = 1; o < 64; o <<= 1) {
    int v = __shfl_up(inc, o);
    if ((t & 63) >= o) inc += v;
  }
  __shared__ int wsum[4];
  if ((t & 63) == 63) wsum[t >> 6] = inc;
  __syncthreads();
  int wpre = 0;
#pragma unroll
  for (int w = 0; w < 4; ++w) if (w < (t >> 6)) wpre += wsum[w];
  int run = wpre + inc - tsum;
  int o8[8];
#pragma unroll
  for (int i = 0; i < 8; ++i) { o8[i] = run; run += s8[i]; }
  const int base = wbase * 2;   // segment index
  *(int4*)&fillpos[base]     = make_int4(o8[0], o8[1], o8[2], o8[3]);
  *(int4*)&fillpos[base + 4] = make_int4(o8[4], o8[5], o8[6], o8[7]);
  if (t == 255) blkSum[blockIdx.x] = wpre + inc;
}

__global__ __launch_bounds__(256)
void scan_tops(int* __restrict__ blkSum) {
  const int t = threadIdx.x;
  const int v = (t < NBLK) ? blkSum[t] : 0;
  int inc = v;
#pragma unroll
  for (int o = 1; o < 64; o <<= 1) {
    int u = __shfl_up(inc, o);
    if ((t & 63) >= o) inc += u;
  }
  __shared__ int wsum[4];
  if ((t & 63) == 63) wsum[t >> 6] = inc;
  __syncthreads();
  int wpre = 0;
#pragma unroll
  for (int w = 0; w < 4; ++w) if (w < (t >> 6)) wpre += wsum[w];
  if (t < NBLK) blkSum[t] = wpre + inc - v;
}

__global__ __launch_bounds__(256)
void scan_apply(int* __restrict__ fillpos, const int* __restrict__ blkSum) {
  const int base = blockIdx.x * 2048 + threadIdx.x * 8;
  const int off = blkSum[blockIdx.x];
  int4 a = *(int4*)&fillpos[base];
  int4 b = *(int4*)&fillpos[base + 4];
  a.x += off; a.y += off; a.z += off; a.w += off;
  b.x += off; b.y += off; b.z += off; b.w += off;
  *(int4*)&fillpos[base]     = a;
  *(int4*)&fillpos[base + 4] = b;
}

// ---------------- pass 2: scatter srcs to sorted order, NO atomics ----------------
__global__ __launch_bounds__(256)
void fill_scatter(const int* __restrict__ src, const int* __restrict__ dst,
                  const int* __restrict__ et, const int* __restrict__ rank,
                  int E, const int* __restrict__ segbase, int* __restrict__ srt) {
  const int e = blockIdx.x * 256 + threadIdx.x;
  if (e < E) {
    const int r = et[e];
    const int seg = 2 * ((r >> 1) * NN + dst[e]) + (r & 1);
    srt[segbase[seg] + rank[e]] = src[e];
  }
}

// Wt1[9][128][128] and Wt2[9][64][128] bf16, transposed, in one dispatch
__global__ __launch_bounds__(256)
void prep_w(const float* __restrict__ W1, const float* __restrict__ root1,
            const float* __restrict__ W2, const float* __restrict__ root2,
            unsigned short* __restrict__ Wt1, unsigned short* __restrict__ Wt2) {
  int idx = blockIdx.x * 256 + threadIdx.x;
  if (idx < 9 * 128 * KD) {
    const int k = idx & 127;
    const int n = (idx >> 7) & 127;
    const int ch = idx >> 14;
    const float v = (ch < 8) ? W1[((size_t)ch * KD + k) * 128 + n] : root1[(size_t)k * 128 + n];
    Wt1[idx] = bf1(v);
  } else {
    idx -= 9 * 128 * KD;
    const int k = idx & 127;
    const int n = (idx >> 7) & 63;
    const int ch = idx >> 13;
    const float v = (ch < 8) ? W2[((size_t)ch * KD + k) * 64 + n] : root2[(size_t)k * 64 + n];
    Wt2[idx] = bf1(v);
  }
}

// ---------------- layer-1 gather: agg[r][d][:] = mean of bf16 X rows ----------------
// 16 lanes per segment (segidx order); NT store for the 100MB agg stream
__global__ __launch_bounds__(256)
void gather_mean(const unsigned* __restrict__ Xb,         // [PADN][64] uint
                 const int* __restrict__ srt,
                 const int* __restrict__ segbase, const unsigned* __restrict__ cntp,
                 unsigned* __restrict__ agg) {            // [8][PADN][64] uint
  const int g = blockIdx.x * 16 + (threadIdx.x >> 4);     // segidx
  const int lane = threadIdx.x & 15;
  const int word = g >> 1, bit = g & 1;
  const int c = (cntp[word] >> (bit * 16)) & 0xffff;
  const int base = segbase[g];
  float acc[8] = {};
  int i = 0;
  for (; i + 1 < c; i += 2) {
    const int s0 = srt[base + i], s1 = srt[base + i + 1];
    const uint4 v0 = *(const uint4*)&Xb[(size_t)s0 * 64 + lane * 4];
    const uint4 v1 = *(const uint4*)&Xb[(size_t)s1 * 64 + lane * 4];
    acc[0] += bflo(v0.x) + bflo(v1.x); acc[1] += bfhi(v0.x) + bfhi(v1.x);
    acc[2] += bflo(v0.y) + bflo(v1.y); acc[3] += bfhi(v0.y) + bfhi(v1.y);
    acc[4] += bflo(v0.z) + bflo(v1.z); acc[5] += bfhi(v0.z) + bfhi(v1.z);
    acc[6] += bflo(v0.w) + bflo(v1.w); acc[7] += bfhi(v0.w) + bfhi(v1.w);
  }
  if (i < c) {
    const uint4 v0 = *(const uint4*)&Xb[(size_t)srt[base + i] * 64 + lane * 4];
    acc[0] += bflo(v0.x); acc[1] += bfhi(v0.x);
    acc[2] += bflo(v0.y); acc[3] += bfhi(v0.y);
    acc[4] += bflo(v0.z); acc[5] += bfhi(v0.z);
    acc[6] += bflo(v0.w); acc[7] += bfhi(v0.w);
  }
  const float sc = (c > 0) ? 1.0f / (float)c : 0.0f;
  u32x4 o;
  o.x = pk_bf16(acc[0] * sc, acc[1] * sc); o.y = pk_bf16(acc[2] * sc, acc[3] * sc);
  o.z = pk_bf16(acc[4] * sc, acc[5] * sc); o.w = pk_bf16(acc[6] * sc, acc[7] * sc);
  const int q = word / NN, d = word - q * NN;
  const int r = q * 2 + bit;
  __builtin_nontemporal_store(o, (u32x4*)&agg[((size_t)r * PADN + d) * 64 + lane * 4]);
}

// ---------------- layer-1 MFMA GEMM ----------------
// hb = relu(sum_{ch<8} agg_ch @ Wt_ch^T + xb @ Wt_8^T + bias), bf16 out, pad rows zeroed
__global__ __launch_bounds__(256)
void rgcn_gemm_mfma(const unsigned short* __restrict__ agg,   // [8][PADN][128] bf16
                    const unsigned short* __restrict__ xrow,  // [PADN][128] bf16
                    const unsigned short* __restrict__ Wt,    // [9][128][128] bf16
                    const float* __restrict__ bias,
                    unsigned short* __restrict__ Cout) {
  constexpr int BN = 128, WM = 64, MF = 4, NF = 4, WAVES_N = 2;
  __shared__ uint4 ldsv[(128 * 128 + BN * 128) / 16];
  char* As = (char*)ldsv;
  char* Bs = (char*)ldsv + 128 * 128;

  const int t = threadIdx.x;
  const int l = t & 63;
  const int w = t >> 6;
  const int wr = w / WAVES_N;
  const int wc = w % WAVES_N;
  const int row0 = blockIdx.x * 128;
  const int l15 = l & 15, lq = l >> 4;

  f32x4 acc[MF][NF];
#pragma unroll
  for (int mi = 0; mi < MF; ++mi)
#pragma unroll
    for (int ni = 0; ni < NF; ++ni) acc[mi][ni] = (f32x4){0.f, 0.f, 0.f, 0.f};

  for (int ch = 0; ch < 9; ++ch) {
    const unsigned short* aP = (ch < 8) ? (agg + (size_t)ch * PADN * KD) : xrow;
    const unsigned short* bP = Wt + (size_t)ch * BN * KD;
#pragma unroll
    for (int kt = 0; kt < 2; ++kt) {
      __syncthreads();
#pragma unroll
      for (int i = 0; i < 4; ++i) {
        const int s = t + i * 256;
        const int r = s >> 3, c16 = s & 7;
        u32x4 v = __builtin_nontemporal_load(
            (const u32x4*)(aP + (size_t)(row0 + r) * KD + kt * 64 + c16 * 8));
        *(u32x4*)(As + r * 128 + ((c16 ^ (r & 7)) * 16)) = v;
      }
#pragma unroll
      for (int i = 0; i < BN / 32; ++i) {
        const int s = t + i * 256;
        const int r = s >> 3, c16 = s & 7;
        uint4 v = *(const uint4*)(bP + (size_t)r * KD + kt * 64 + c16 * 8);
        *(uint4*)(Bs + r * 128 + ((c16 ^ (r & 7)) * 16)) = v;
      }
      __syncthreads();
#pragma unroll
      for (int ks = 0; ks < 2; ++ks) {
        short8 bfr[NF];
#pragma unroll
        for (int ni = 0; ni < NF; ++ni) {
          const int br = wc * 64 + ni * 16 + l15;
          bfr[ni] = *(const short8*)(Bs + br * 128 + (((ks * 4 + lq) ^ (br & 7)) * 16));
        }
#pragma unroll
        for (int mi = 0; mi < MF; ++mi) {
          const int ar = wr * WM + mi * 16 + l15;
          short8 af = *(const short8*)(As + ar * 128 + (((ks * 4 + lq) ^ (ar & 7)) * 16));
#pragma unroll
          for (int ni = 0; ni < NF; ++ni)
            acc[mi][ni] = __builtin_amdgcn_mfma_f32_16x16x32_bf16(af, bfr[ni], acc[mi][ni], 0, 0, 0);
        }
      }
    }
  }
#pragma unroll
  for (int ni = 0; ni < NF; ++ni) {
    const int col = wc * 64 + ni * 16 + l15;
    const float bv = bias[col];
#pragma unroll
    for (int mi = 0; mi < MF; ++mi) {
#pragma unroll
      for (int q = 0; q < 4; ++q) {
        const int grow = row0 + wr * WM + mi * 16 + lq * 4 + q;
        if (grow < NN) {
          float v = fmaxf(acc[mi][ni][q] + bv, 0.f);
          Cout[(size_t)grow * BN + col] = bf1(v);
        } else {
          Cout[(size_t)grow * BN + col] = 0;   // clean pad rows for gemm_y
        }
      }
    }
  }
}

// ---------------- layer-2 transform GEMM: Y[M,576] = hb[M,128] @ Wt2^T ----------------
__global__ __launch_bounds__(256)
void gemm_y(const unsigned short* __restrict__ A,    // [PADN][128] bf16
            const unsigned short* __restrict__ Wt,   // [576][128] bf16
            unsigned short* __restrict__ Y) {        // [PADN][576] bf16
  constexpr int BN = 64, NCOLS = 576, WM = 32, MF = 2, NF = 4;
  __shared__ uint4 ldsv[(128 * 128 + BN * 128) / 16];
  char* As = (char*)ldsv;
  char* Bs = (char*)ldsv + 128 * 128;

  const int t = threadIdx.x;
  const int l = t & 63;
  const int w = t >> 6;
  const int row0 = blockIdx.x * 128;
  const int col0 = blockIdx.y * BN;
  const unsigned short* bP = Wt + (size_t)col0 * KD;
  const int l15 = l & 15, lq = l >> 4;

  f32x4 acc[MF][NF];
#pragma unroll
  for (int mi = 0; mi < MF; ++mi)
#pragma unroll
    for (int ni = 0; ni < NF; ++ni) acc[mi][ni] = (f32x4){0.f, 0.f, 0.f, 0.f};

#pragma unroll
  for (int kt = 0; kt < 2; ++kt) {
    __syncthreads();
#pragma unroll
    for (int i = 0; i < 4; ++i) {
      const int s = t + i * 256;
      const int r = s >> 3, c16 = s & 7;
      uint4 v = *(const uint4*)(A + (size_t)(row0 + r) * KD + kt * 64 + c16 * 8);
      *(uint4*)(As + r * 128 + ((c16 ^ (r & 7)) * 16)) = v;
    }
#pragma unroll
    for (int i = 0; i < BN / 32; ++i) {
      const int s = t + i * 256;
      const int r = s >> 3, c16 = s & 7;
      uint4 v = *(const uint4*)(bP + (size_t)r * KD + kt * 64 + c16 * 8);
      *(uint4*)(Bs + r * 128 + ((c16 ^ (r & 7)) * 16)) = v;
    }
    __syncthreads();
#pragma unroll
    for (int ks = 0; ks < 2; ++ks) {
      short8 bfr[NF];
#pragma unroll
      for (int ni = 0; ni < NF; ++ni) {
        const int br = w * 64 + ni * 16 + l15;   // wait: BN=64, one wave-col
        (void)br;
      }
      // BN=64: all 4 waves share the 64 cols; wave w covers rows wr*32
      // (recompute cleanly below)
#pragma unroll
      for (int ni = 0; ni < NF; ++ni) {
        const int br = ni * 16 + l15;
        bfr[ni] = *(const short8*)(Bs + br * 128 + (((ks * 4 + lq) ^ (br & 7)) * 16));
      }
#pragma unroll
      for (int mi = 0; mi < MF; ++mi) {
        const int ar = w * WM + mi * 16 + l15;
        short8 af = *(const short8*)(As + ar * 128 + (((ks * 4 + lq) ^ (ar & 7)) * 16));
#pragma unroll
        for (int ni = 0; ni < NF; ++ni)
          acc[mi][ni] = __builtin_amdgcn_mfma_f32_16x16x32_bf16(af, bfr[ni], acc[mi][ni], 0, 0, 0);
      }
    }
  }
#pragma unroll
  for (int ni = 0; ni < NF; ++ni) {
    const int col = col0 + ni * 16 + l15;
#pragma unroll
    for (int mi = 0; mi < MF; ++mi) {
#pragma unroll
      for (int q = 0; q < 4; ++q) {
        const int grow = row0 + w * WM + mi * 16 + lq * 4 + q;
        Y[(size_t)grow * NCOLS + col] = bf1(acc[mi][ni][q]);
      }
    }
  }
}

// ---------------- layer-2 gather-reduce: out[d] = self + bias + sum_r mean_r ----
// 16 lanes per dst node, FO=64, fp32 out.
__global__ __launch_bounds__(256)
void gather_out(const unsigned* __restrict__ Y,      // [PADN][288] uints
                const int* __restrict__ srt,
                const int* __restrict__ segbase, const unsigned* __restrict__ cntp,
                const float* __restrict__ bias,
                float* __restrict__ Out) {
  const int d = blockIdx.x * 16 + (threadIdx.x >> 4);
  const int lane = threadIdx.x & 15;
  const int l = threadIdx.x & 63;

  int meta = 0;
  if (lane < 8) {
    meta = (cntp[(lane >> 1) * NN + d] >> ((lane & 1) * 16)) & 0xffff;
  } else {
    const int rr = lane - 8;
    meta = segbase[2 * ((rr >> 1) * NN + d) + (rr & 1)];
  }

  float acc[4] = {};
#pragma unroll
  for (int r = 0; r < 8; ++r) {
    const int c    = __shfl(meta, (l & 48) + r);
    const int base = __shfl(meta, (l & 48) + 8 + r);
    float tmp[4] = {};
    int i = 0;
    for (; i + 1 < c; i += 2) {
      const int s0 = srt[base + i], s1 = srt[base + i + 1];
      const uint2 v0 = *(const uint2*)&Y[(size_t)s0 * 288 + r * 32 + lane * 2];
      const uint2 v1 = *(const uint2*)&Y[(size_t)s1 * 288 + r * 32 + lane * 2];
      tmp[0] += bflo(v0.x) + bflo(v1.x); tmp[1] += bfhi(v0.x) + bfhi(v1.x);
      tmp[2] += bflo(v0.y) + bflo(v1.y); tmp[3] += bfhi(v0.y) + bfhi(v1.y);
    }
    if (i < c) {
      const uint2 v0 = *(const uint2*)&Y[(size_t)srt[base + i] * 288 + r * 32 + lane * 2];
      tmp[0] += bflo(v0.x); tmp[1] += bfhi(v0.x);
      tmp[2] += bflo(v0.y); tmp[3] += bfhi(v0.y);
    }
    const float inv = (c > 0) ? 1.0f / (float)c : 0.0f;
#pragma unroll
    for (int j = 0; j < 4; ++j) acc[j] += tmp[j] * inv;
  }

  // self slice (ch 8) + bias
  const uint2 sv = *(const uint2*)&Y[(size_t)d * 288 + 256 + lane * 2];
  const float4 b0 = *(const float4*)&bias[lane * 4];
  float4 o;
  o.x = bflo(sv.x) + b0.x + acc[0];
  o.y = bfhi(sv.x) + b0.y + acc[1];
  o.z = bflo(sv.y) + b0.z + acc[2];
  o.w = bfhi(sv.y) + b0.w + acc[3];
  *(float4*)&Out[(size_t)d * 64 + lane * 4] = o;
}

// ---------------- launch ----------------
extern "C" void kernel_launch(void* const* d_in, const int* in_sizes, int n_in,
                              void* d_out, int out_size, void* d_ws, size_t ws_size,
                              hipStream_t stream) {
  const float* x     = (const float*)d_in[0];
  const int*   ei    = (const int*)d_in[1];
  const int*   et    = (const int*)d_in[2];
  const float* W1    = (const float*)d_in[3];
  const float* root1 = (const float*)d_in[4];
  const float* b1    = (const float*)d_in[5];
  const float* W2    = (const float*)d_in[6];
  const float* root2 = (const float*)d_in[7];
  const float* b2    = (const float*)d_in[8];
  float* out = (float*)d_out;

  const int E = in_sizes[2];
  const int* src  = ei;
  const int* dstv = ei + E;

  // workspace layout (~135 MB, 16B-aligned)
  char* ws = (char*)d_ws;
  unsigned short* xb  = (unsigned short*)ws;                 // 12,812,288 B
  unsigned short* hb  = (unsigned short*)(ws + 12812288);    // 12,812,288 B
  unsigned short* agg = (unsigned short*)(ws + 25624576);    // 102,498,304 B (agg / Y2 / rank)
  unsigned short* Wt1 = (unsigned short*)(ws + 128122880);   //    294,912 B
  unsigned short* Wt2 = (unsigned short*)(ws + 128417792);   //    147,456 B
  unsigned* cntp = (unsigned*)(ws + 128565248);              // PADSEG/2*4 = 802,816 B
  int* fillpos = (int*)(ws + 130170880);                     // PADSEG*4 = 1,605,632 B
  int* blkSum  = (int*)(ws + 131776512);                     //      1,024 B
  int* srt     = (int*)(ws + 131777536);                     //  3,200,000 B
  int* rank    = (int*)agg;       // consumed by fill_scatter before agg written
  unsigned short* Y2 = agg;       // layer-2 Y aliases agg (agg dead after gemm1)

  // structure build: packed rank-assign (+x convert) -> scan -> scatter
  hipMemsetAsync(cntp, 0, sizeof(unsigned) * (size_t)(PADSEG / 2), stream);
  convert_count_rank<<<PADN * 16 / 256, 256, 0, stream>>>(x, (unsigned*)xb, dstv, et, E, cntp, rank);
  scan_block<<<NBLK, 256, 0, stream>>>(cntp, fillpos, blkSum);
  scan_tops<<<1, 256, 0, stream>>>(blkSum);
  scan_apply<<<NBLK, 256, 0, stream>>>(fillpos, blkSum);
  fill_scatter<<<(E + 255) / 256, 256, 0, stream>>>(src, dstv, et, rank, E, fillpos, srt);

  prep_w<<<(9 * 128 * KD + 9 * 64 * KD) / 256, 256, 0, stream>>>(W1, root1, W2, root2, Wt1, Wt2);

  const int mBlocks = PADN / 128;       // 391

  // layer 1: aggregate-then-transform (agg path)
  gather_mean<<<NSEG / 16, 256, 0, stream>>>((const unsigned*)xb, srt, fillpos, cntp, (unsigned*)agg);
  rgcn_gemm_mfma<<<mBlocks, 256, 0, stream>>>(agg, xb, Wt1, b1, hb);

  // layer 2: transform-then-aggregate (Y path, straight to out)
  gemm_y<<<dim3(mBlocks, 9), 256, 0, stream>>>(hb, Wt2, Y2);
  gather_out<<<NN / 16, 256, 0, stream>>>((const unsigned*)Y2, srt, fillpos, cntp, b2, out);
}